// Round 14
// baseline (75.098 us; speedup 1.0000x reference)
//
#include <hip/hip_runtime.h>
#include <math.h>

#define BB 512
#define DD 128
#define KK 8
#define BOUNDARY 4

// ---------------- workspace layout (bytes) ----------------
// partS : 0    .. 2048   (512 float)  per-block loss partial sum
// partC : 2048 .. 4096   (512 int)    per-block hinge count
// Written unconditionally by every block -> no memset needed.
// NO device-scope atomics/fences anywhere (rounds 8-10: any single-kernel
// finalize costs 40-60 us of cross-XCD coherence tail; tiny 2nd dispatch wins).
// Occupancy lessons: latency-bound kernel; R12 (4 waves/CU) regressed,
// R13 (16 waves/CU) won. This round: 1024-thr blocks = 2 blocks/CU x 16
// waves = 32 waves/CU (hardware max), VGPR ~48 fits the 64/thread budget.
//
// Algebraic facts exploited (boundary = int(512/128) = 4):
//  * anchor rows belong to classes with <= 3 members, so the positive top-8
//    selects ALL same-class rows: mask_ap[i][j] == anchors[i] & tgt[j]==tgt[i] & i!=j.
//  * block k owns column k: its neg top-8 rows r are exactly the (i=r, k)
//    entries of mask_an, and d[r,k] = -s_vn[r] (selected negs are always
//    different-class; s_vn holds -d).
//  * the diagonal is never consumed (neg-masked; positives exclude j==r).
//  * the <= 16 positive distances d[r,j] per block are recomputed directly
//    from x (one 128-dim dot each) — hinge values only, not selections.

__global__ __launch_bounds__(1024, 8) void fused_kernel(
    const float* __restrict__ x, const int* __restrict__ tgt,
    float* __restrict__ partS, int* __restrict__ partC)
{
    __shared__ float4 xi4[DD / 4];
    __shared__ float s_vn[BB];         // -d, masked to -inf on same-class
    __shared__ float s_sq[BB];         // squared norms of all rows
    __shared__ int   s_tgt[BB];
    __shared__ int   s_cnt[128];       // class histogram
    __shared__ int   s_sel[KK];        // selected neg rows, -1 invalid
    __shared__ int   s_pr[16], s_pj[16];
    __shared__ int   s_np;

    int k = blockIdx.x;
    int t = threadIdx.x;               // 0..1023
    if (t < DD / 4) xi4[t] = ((const float4*)(x + k * DD))[t];
    if (t < 128) s_cnt[t] = 0;
    if (t == 0) s_np = 0;
    if (t < BB) s_tgt[t] = tgt[t];
    __syncthreads();
    int tk = s_tgt[k];

    float q0 = 0.f, q1 = 0.f, q2 = 0.f, q3 = 0.f;
    for (int c = 0; c < DD / 4; ++c) {
        float4 a = xi4[c];
        q0 += a.x * a.x; q1 += a.y * a.y; q2 += a.z * a.z; q3 += a.w * a.w;
    }
    float sqk = (q0 + q1) + (q2 + q3);

    // distance loop: 8 lanes cooperate per row (coalesced 128-B segments).
    // g = t>>3 (0..127 row-groups), sub = t&7; 4 passes x 128 groups = 512 rows.
    // Same per-row chain structure as R13 -> identical distance bits -> picks.
    {
        int g = t >> 3, sub = t & 7;
        for (int pass = 0; pass < 4; ++pass) {
            int r = pass * 128 + g;
            const float4* xr = (const float4*)(x + r * DD);
            float d0, d1, d2, d3, s0, s1, s2, s3;
            {
                float4 a = xi4[sub],      b = xr[sub];
                d0 = a.x*b.x + a.y*b.y + a.z*b.z + a.w*b.w;
                s0 = b.x*b.x + b.y*b.y + b.z*b.z + b.w*b.w;
            }
            {
                float4 a = xi4[sub + 8],  b = xr[sub + 8];
                d1 = a.x*b.x + a.y*b.y + a.z*b.z + a.w*b.w;
                s1 = b.x*b.x + b.y*b.y + b.z*b.z + b.w*b.w;
            }
            {
                float4 a = xi4[sub + 16], b = xr[sub + 16];
                d2 = a.x*b.x + a.y*b.y + a.z*b.z + a.w*b.w;
                s2 = b.x*b.x + b.y*b.y + b.z*b.z + b.w*b.w;
            }
            {
                float4 a = xi4[sub + 24], b = xr[sub + 24];
                d3 = a.x*b.x + a.y*b.y + a.z*b.z + a.w*b.w;
                s3 = b.x*b.x + b.y*b.y + b.z*b.z + b.w*b.w;
            }
            float dot = (d0 + d1) + (d2 + d3);
            float sq  = (s0 + s1) + (s2 + s3);
            for (int off = 4; off > 0; off >>= 1) {
                dot += __shfl_down(dot, off, 8);
                sq  += __shfl_down(sq,  off, 8);
            }
            if (sub == 0) {
                float dsq = fmaxf((sqk + sq) - 2.f * dot, 0.f);
                float dv = (dsq == 0.f) ? 0.f : sqrtf(dsq);
                s_sq[r] = sq;
                s_vn[r] = (s_tgt[r] == tk) ? -INFINITY : -dv;
            }
        }
    }
    __syncthreads();

    int wave = t >> 6, lane = t & 63;
    if (wave == 0) {
        // neg top-8: largest -d among different-class rows (lax.top_k order:
        // descending value, lower index on tie) — byte-identical to round 13
        float v[8];
        for (int q = 0; q < 8; ++q) v[q] = s_vn[q * 64 + lane];
        for (int pass = 0; pass < KK; ++pass) {
            float bv = -INFINITY; int bq = -1;
            for (int q = 0; q < 8; ++q)
                if (v[q] > bv) { bv = v[q]; bq = q; }   // strict > keeps lowest q
            int bi = (bq >= 0) ? (bq * 64 + lane) : (1 << 30);
            for (int off = 32; off > 0; off >>= 1) {
                float ov = __shfl_down(bv, off);
                int   oi = __shfl_down(bi, off);
                if (ov > bv || (ov == bv && oi < bi)) { bv = ov; bi = oi; }
            }
            bv = __shfl(bv, 0); bi = __shfl(bi, 0);
            if (lane == 0) s_sel[pass] = (bv == -INFINITY) ? -1 : bi;
            if ((bi & 63) == lane) v[bi >> 6] = -INFINITY;
        }
    } else if (wave == 1) {
        // class histogram (includes self-counts)
        for (int q = 0; q < 8; ++q) atomicAdd(&s_cnt[s_tgt[q * 64 + lane]], 1);
    }
    __syncthreads();

    // collect (anchor r, positive j) pairs: waves 0..7, one top-k slot each
    if (wave < KK) {
        int r = s_sel[wave];
        if (r >= 0) {
            int tr = s_tgt[r];
            if (s_cnt[tr] < BOUNDARY) {          // anchor: class size <= 3
                for (int j = lane; j < BB; j += 64)
                    if (j != r && s_tgt[j] == tr) {
                        int idx = atomicAdd(&s_np, 1);
                        s_pr[idx] = r; s_pj[idx] = j;
                    }
            }
        }
    }
    __syncthreads();

    // hinge terms: <= 16 pairs, all resident in wave 0
    float s = 0.f; int c = 0;
    if (t < s_np) {
        int r = s_pr[t], j = s_pj[t];
        const float4* xr = (const float4*)(x + r * DD);
        const float4* xj = (const float4*)(x + j * DD);
        float d0 = 0.f, d1 = 0.f, d2 = 0.f, d3 = 0.f;
        for (int cc = 0; cc < DD / 4; ++cc) {
            float4 a = xr[cc], b = xj[cc];
            d0 += a.x * b.x; d1 += a.y * b.y; d2 += a.z * b.z; d3 += a.w * b.w;
        }
        float dot = (d0 + d1) + (d2 + d3);
        float dsq = fmaxf((s_sq[r] + s_sq[j]) - 2.f * dot, 0.f);
        float dpos = (dsq == 0.f) ? 0.f : sqrtf(dsq);
        float tv = dpos + s_vn[r] + 1.0f;        // d[r,j] - d[r,k] + margin
        if (tv > 0.f) { s = tv; c = (tv > 1e-7f) ? 1 : 0; }
    }
    if (wave == 0) {
        for (int off = 32; off > 0; off >>= 1) {
            s += __shfl_down(s, off);
            c += __shfl_down(c, off);
        }
        if (lane == 0) { partS[k] = s; partC[k] = c; }
    }
}

__global__ __launch_bounds__(64) void fin_kernel(
    const float* __restrict__ partS, const int* __restrict__ partC,
    float* __restrict__ out)
{
    int lane = threadIdx.x;              // 0..63; 512 partials = 128 x float4
    const float4* pS = (const float4*)partS;
    const int4*   pC = (const int4*)partC;
    float4 a = pS[lane], b = pS[lane + 64];
    int4   u = pC[lane], v = pC[lane + 64];
    float S = ((a.x + a.y) + (a.z + a.w)) + ((b.x + b.y) + (b.z + b.w));
    int   C = ((u.x + u.y) + (u.z + u.w)) + ((v.x + v.y) + (v.z + v.w));
    for (int off = 32; off > 0; off >>= 1) {
        S += __shfl_down(S, off);
        C += __shfl_down(C, off);
    }
    if (lane == 0) out[0] = S / ((float)C + 1e-7f);
}

extern "C" void kernel_launch(void* const* d_in, const int* in_sizes, int n_in,
                              void* d_out, int out_size, void* d_ws, size_t ws_size,
                              hipStream_t stream) {
    const float* x   = (const float*)d_in[0];
    const int*   tgt = (const int*)d_in[1];
    float* out = (float*)d_out;

    char* ws = (char*)d_ws;
    float* partS = (float*)(ws + 0);
    int*   partC = (int*)(ws + 2048);

    fused_kernel<<<BB, 1024, 0, stream>>>(x, tgt, partS, partC);
    fin_kernel<<<1, 64, 0, stream>>>(partS, partC, out);
}

// Round 15
// 70.892 us; speedup vs baseline: 1.0593x; 1.0593x over previous
//
#include <hip/hip_runtime.h>
#include <math.h>

#define BB 512
#define DD 128
#define KK 8
#define BOUNDARY 4

// ---------------- workspace layout (bytes) ----------------
// partS : 0    .. 2048   (512 float)  per-block loss partial sum
// partC : 2048 .. 4096   (512 int)    per-block hinge count
// Written unconditionally by every block -> no memset needed.
// NO device-scope atomics/fences anywhere (rounds 8-10: any single-kernel
// finalize costs 40-60 us of cross-XCD coherence tail; tiny 2nd dispatch wins).
// Occupancy curve (measured): 4 waves/CU = 77.4us, 8 = 73.9, 16 = 71.1,
// 32 = 75.1 -> this file pins the 16 waves/CU optimum (512 thr x 512 blocks).
//
// Algebraic facts exploited (boundary = int(512/128) = 4):
//  * anchor rows belong to classes with <= 3 members, so the positive top-8
//    selects ALL same-class rows: mask_ap[i][j] == anchors[i] & tgt[j]==tgt[i] & i!=j.
//  * block k owns column k: its neg top-8 rows r are exactly the (i=r, k)
//    entries of mask_an, and d[r,k] = -s_vn[r] (selected negs are always
//    different-class; s_vn holds -d).
//  * the diagonal is never consumed (neg-masked; positives exclude j==r).
//  * the <= 16 positive distances d[r,j] per block are recomputed directly
//    from x (one 128-dim dot each) — hinge values only, not selections.

__global__ __launch_bounds__(512, 4) void fused_kernel(
    const float* __restrict__ x, const int* __restrict__ tgt,
    float* __restrict__ partS, int* __restrict__ partC)
{
    __shared__ float4 xi4[DD / 4];
    __shared__ float s_vn[BB];         // -d, masked to -inf on same-class
    __shared__ float s_sq[BB];         // squared norms of all rows
    __shared__ int   s_tgt[BB];
    __shared__ int   s_cnt[128];       // class histogram
    __shared__ int   s_sel[KK];        // selected neg rows, -1 invalid
    __shared__ int   s_pr[16], s_pj[16];
    __shared__ int   s_np;

    int k = blockIdx.x;
    int t = threadIdx.x;               // 0..511
    if (t < DD / 4) xi4[t] = ((const float4*)(x + k * DD))[t];
    if (t < 128) s_cnt[t] = 0;
    if (t == 0) s_np = 0;
    s_tgt[t] = tgt[t];
    __syncthreads();
    int tk = s_tgt[k];

    float q0 = 0.f, q1 = 0.f, q2 = 0.f, q3 = 0.f;
    for (int c = 0; c < DD / 4; ++c) {
        float4 a = xi4[c];
        q0 += a.x * a.x; q1 += a.y * a.y; q2 += a.z * a.z; q3 += a.w * a.w;
    }
    float sqk = (q0 + q1) + (q2 + q3);

    // distance loop: 8 lanes cooperate per row (coalesced 128-B segments).
    // g = t>>3 (0..63 row-groups), sub = t&7; 8 passes x 64 groups = 512 rows.
    {
        int g = t >> 3, sub = t & 7;
        for (int pass = 0; pass < 8; ++pass) {
            int r = pass * 64 + g;
            const float4* xr = (const float4*)(x + r * DD);
            float d0, d1, d2, d3, s0, s1, s2, s3;
            {
                float4 a = xi4[sub],      b = xr[sub];
                d0 = a.x*b.x + a.y*b.y + a.z*b.z + a.w*b.w;
                s0 = b.x*b.x + b.y*b.y + b.z*b.z + b.w*b.w;
            }
            {
                float4 a = xi4[sub + 8],  b = xr[sub + 8];
                d1 = a.x*b.x + a.y*b.y + a.z*b.z + a.w*b.w;
                s1 = b.x*b.x + b.y*b.y + b.z*b.z + b.w*b.w;
            }
            {
                float4 a = xi4[sub + 16], b = xr[sub + 16];
                d2 = a.x*b.x + a.y*b.y + a.z*b.z + a.w*b.w;
                s2 = b.x*b.x + b.y*b.y + b.z*b.z + b.w*b.w;
            }
            {
                float4 a = xi4[sub + 24], b = xr[sub + 24];
                d3 = a.x*b.x + a.y*b.y + a.z*b.z + a.w*b.w;
                s3 = b.x*b.x + b.y*b.y + b.z*b.z + b.w*b.w;
            }
            float dot = (d0 + d1) + (d2 + d3);
            float sq  = (s0 + s1) + (s2 + s3);
            for (int off = 4; off > 0; off >>= 1) {
                dot += __shfl_down(dot, off, 8);
                sq  += __shfl_down(sq,  off, 8);
            }
            if (sub == 0) {
                float dsq = fmaxf((sqk + sq) - 2.f * dot, 0.f);
                float dv = (dsq == 0.f) ? 0.f : sqrtf(dsq);
                s_sq[r] = sq;
                s_vn[r] = (s_tgt[r] == tk) ? -INFINITY : -dv;
            }
        }
    }
    __syncthreads();

    int wave = t >> 6, lane = t & 63;
    if (wave == 0) {
        // neg top-8: largest -d among different-class rows (lax.top_k order:
        // descending value, lower index on tie)
        float v[8];
        for (int q = 0; q < 8; ++q) v[q] = s_vn[q * 64 + lane];
        for (int pass = 0; pass < KK; ++pass) {
            float bv = -INFINITY; int bq = -1;
            for (int q = 0; q < 8; ++q)
                if (v[q] > bv) { bv = v[q]; bq = q; }   // strict > keeps lowest q
            int bi = (bq >= 0) ? (bq * 64 + lane) : (1 << 30);
            for (int off = 32; off > 0; off >>= 1) {
                float ov = __shfl_down(bv, off);
                int   oi = __shfl_down(bi, off);
                if (ov > bv || (ov == bv && oi < bi)) { bv = ov; bi = oi; }
            }
            bv = __shfl(bv, 0); bi = __shfl(bi, 0);
            if (lane == 0) s_sel[pass] = (bv == -INFINITY) ? -1 : bi;
            if ((bi & 63) == lane) v[bi >> 6] = -INFINITY;
        }
    } else if (wave == 1) {
        // class histogram (includes self-counts)
        for (int q = 0; q < 8; ++q) atomicAdd(&s_cnt[s_tgt[q * 64 + lane]], 1);
    }
    __syncthreads();

    // collect (anchor r, positive j) pairs: 8 waves, one top-k slot each
    {
        int r = s_sel[wave];
        if (r >= 0) {
            int tr = s_tgt[r];
            if (s_cnt[tr] < BOUNDARY) {          // anchor: class size <= 3
                for (int j = lane; j < BB; j += 64)
                    if (j != r && s_tgt[j] == tr) {
                        int idx = atomicAdd(&s_np, 1);
                        s_pr[idx] = r; s_pj[idx] = j;
                    }
            }
        }
    }
    __syncthreads();

    // hinge terms: <= 16 pairs, all resident in wave 0
    float s = 0.f; int c = 0;
    if (t < s_np) {
        int r = s_pr[t], j = s_pj[t];
        const float4* xr = (const float4*)(x + r * DD);
        const float4* xj = (const float4*)(x + j * DD);
        float d0 = 0.f, d1 = 0.f, d2 = 0.f, d3 = 0.f;
        for (int cc = 0; cc < DD / 4; ++cc) {
            float4 a = xr[cc], b = xj[cc];
            d0 += a.x * b.x; d1 += a.y * b.y; d2 += a.z * b.z; d3 += a.w * b.w;
        }
        float dot = (d0 + d1) + (d2 + d3);
        float dsq = fmaxf((s_sq[r] + s_sq[j]) - 2.f * dot, 0.f);
        float dpos = (dsq == 0.f) ? 0.f : sqrtf(dsq);
        float tv = dpos + s_vn[r] + 1.0f;        // d[r,j] - d[r,k] + margin
        if (tv > 0.f) { s = tv; c = (tv > 1e-7f) ? 1 : 0; }
    }
    if (wave == 0) {
        for (int off = 32; off > 0; off >>= 1) {
            s += __shfl_down(s, off);
            c += __shfl_down(c, off);
        }
        if (lane == 0) { partS[k] = s; partC[k] = c; }
    }
}

__global__ __launch_bounds__(64) void fin_kernel(
    const float* __restrict__ partS, const int* __restrict__ partC,
    float* __restrict__ out)
{
    int lane = threadIdx.x;              // 0..63; 512 partials = 128 x float4
    const float4* pS = (const float4*)partS;
    const int4*   pC = (const int4*)partC;
    float4 a = pS[lane], b = pS[lane + 64];
    int4   u = pC[lane], v = pC[lane + 64];
    float S = ((a.x + a.y) + (a.z + a.w)) + ((b.x + b.y) + (b.z + b.w));
    int   C = ((u.x + u.y) + (u.z + u.w)) + ((v.x + v.y) + (v.z + v.w));
    for (int off = 32; off > 0; off >>= 1) {
        S += __shfl_down(S, off);
        C += __shfl_down(C, off);
    }
    if (lane == 0) out[0] = S / ((float)C + 1e-7f);
}

extern "C" void kernel_launch(void* const* d_in, const int* in_sizes, int n_in,
                              void* d_out, int out_size, void* d_ws, size_t ws_size,
                              hipStream_t stream) {
    const float* x   = (const float*)d_in[0];
    const int*   tgt = (const int*)d_in[1];
    float* out = (float*)d_out;

    char* ws = (char*)d_ws;
    float* partS = (float*)(ws + 0);
    int*   partC = (int*)(ws + 2048);

    fused_kernel<<<BB, 512, 0, stream>>>(x, tgt, partS, partC);
    fin_kernel<<<1, 64, 0, stream>>>(partS, partC, out);
}